// Round 1
// baseline (695.263 us; speedup 1.0000x reference)
//
#include <hip/hip_runtime.h>
#include <cstdint>
#include <cstddef>

// Fixed problem constants (from reference setup)
#define B_    2
#define NQ_   21760
#define NK_   21760
#define D_    256
#define NH_   8
#define NL_   4
#define NP_   4
#define HD_   32
#define M_    (B_ * NQ_)   // 43520 rows for every GEMM

// ---------------------------------------------------------------------------
// Tiled fp32 GEMM: C[M,N] = A[M,K=256] @ Bw[K,N] + bias[N]
// EPI==1: fuse loc transform: out = rp[row, l, c] + val * (1/(128>>l))
// Tile 64x64, 256 threads, 4x4 microtile, BK=16.
// ---------------------------------------------------------------------------
template <int N, int EPI>
__global__ __launch_bounds__(256) void gemm_k(const float* __restrict__ A,
                                              const float* __restrict__ Bw,
                                              const float* __restrict__ bias,
                                              float* __restrict__ C,
                                              const float* __restrict__ rp) {
    constexpr int K = 256;
    constexpr int BM = 64, BN = 64, BK = 16;
    __shared__ float As[BK][68];  // As[k][m], padded
    __shared__ float Bs[BK][68];  // Bs[k][n], padded

    const int tid = threadIdx.x;
    const int tx = tid & 15;        // 16 col-threads
    const int ty = tid >> 4;        // 16 row-threads
    const int m0 = blockIdx.x * BM;
    const int n0 = blockIdx.y * BN;

    // A-load: 64 rows x 16 k, float4 per thread: row = tid>>2, k4 = (tid&3)*4
    const int arow = tid >> 2;            // 0..63
    const int ak4  = (tid & 3) << 2;      // 0,4,8,12
    // B-load: 16 k-rows x 64 cols, float4 per thread: krow = tid>>4, c4=(tid&15)*4
    const int brow = tid >> 4;            // 0..15
    const int bc4  = (tid & 15) << 2;     // 0..60

    const float* Aptr = A + (size_t)(m0 + arow) * K + ak4;
    const float* Bptr = Bw + (size_t)brow * N + n0 + bc4;

    float acc[4][4] = {};

    for (int k0 = 0; k0 < K; k0 += BK) {
        float4 av = *(const float4*)(Aptr + k0);
        float4 bv = *(const float4*)(Bptr + (size_t)k0 * N);
        __syncthreads();
        As[ak4 + 0][arow] = av.x;
        As[ak4 + 1][arow] = av.y;
        As[ak4 + 2][arow] = av.z;
        As[ak4 + 3][arow] = av.w;
        *(float4*)&Bs[brow][bc4] = bv;
        __syncthreads();
#pragma unroll
        for (int kk = 0; kk < BK; ++kk) {
            float ar[4], br[4];
            *(float4*)ar = *(const float4*)&As[kk][ty << 2];
            *(float4*)br = *(const float4*)&Bs[kk][tx << 2];
#pragma unroll
            for (int i = 0; i < 4; ++i)
#pragma unroll
                for (int j = 0; j < 4; ++j) acc[i][j] += ar[i] * br[j];
        }
    }

    const int colb = n0 + (tx << 2);
#pragma unroll
    for (int i = 0; i < 4; ++i) {
        const int row = m0 + (ty << 2) + i;
        float4 v;
        float* vp = &v.x;
#pragma unroll
        for (int j = 0; j < 4; ++j) {
            const int col = colb + j;
            float val = acc[i][j] + bias[col];
            if (EPI == 1) {
                const int c = col & 1;
                const int l = (col >> 3) & 3;
                const float inv = 1.f / (float)(128 >> l);
                val = rp[(size_t)row * 8 + l * 2 + c] + val * inv;
            }
            vp[j] = val;
        }
        *(float4*)&C[(size_t)row * N + colb] = v;
    }
}

// ---------------------------------------------------------------------------
// Deformable sampling core.
// One 32-lane unit per (b,q,h); lane = channel d in [0,32).
// Reads logits from `attn` (in-place softmax over 16), loc from loc output,
// gathers from value (B,NK,256), writes core (B*NQ,256).
// ---------------------------------------------------------------------------
__global__ __launch_bounds__(256) void deform_core(const float* __restrict__ value,
                                                   const float* __restrict__ loc,
                                                   float* __restrict__ attn,
                                                   float* __restrict__ core) {
    const int tid  = threadIdx.x;
    const int lane = tid & 31;
    const int u    = blockIdx.x * 8 + (tid >> 5);  // (b,q,h) index, h fastest
    const int h    = u & 7;
    const int bq   = u >> 3;
    const int b    = (bq >= NQ_) ? 1 : 0;

    const float myloc = loc[(size_t)u * 32 + lane];  // (NL,NP,2) = 32 floats

    float lg = -1e30f;
    if (lane < 16) lg = attn[(size_t)u * 16 + lane];
    float m = lg;
#pragma unroll
    for (int mk = 8; mk; mk >>= 1) m = fmaxf(m, __shfl_xor(m, mk, 32));
    const float e = __expf(lg - m);
    float s = e;
#pragma unroll
    for (int mk = 8; mk; mk >>= 1) s += __shfl_xor(s, mk, 32);
    const float a = e / s;
    if (lane < 16) attn[(size_t)u * 16 + lane] = a;

    const float* vb = value + (size_t)b * NK_ * D_ + h * HD_ + lane;
    float acc = 0.f;
    const int starts[4] = {0, 16384, 20480, 21504};
#pragma unroll
    for (int j = 0; j < 16; ++j) {
        const int l  = j >> 2;
        const int Wl = 128 >> l;  // square levels: H == W
        const float aw = __shfl(a, j, 32);
        const float xr = __shfl(myloc, 2 * j, 32);
        const float yr = __shfl(myloc, 2 * j + 1, 32);
        const float x = xr * (float)Wl - 0.5f;
        const float y = yr * (float)Wl - 0.5f;
        const float x0f = floorf(x), y0f = floorf(y);
        const int x0 = (int)x0f, y0 = (int)y0f;
        const float fx = x - x0f, fy = y - y0f;
        const float gx = 1.f - fx, gy = 1.f - fy;
        const bool vx0 = (x0 >= 0) && (x0 < Wl);
        const bool vx1 = (x0 >= -1) && (x0 < Wl - 1);
        const bool vy0 = (y0 >= 0) && (y0 < Wl);
        const bool vy1 = (y0 >= -1) && (y0 < Wl - 1);
        const int cx0 = min(max(x0, 0), Wl - 1);
        const int cx1 = min(max(x0 + 1, 0), Wl - 1);
        const int cy0 = min(max(y0, 0), Wl - 1);
        const int cy1 = min(max(y0 + 1, 0), Wl - 1);
        const float w00 = (vx0 && vy0) ? gx * gy : 0.f;
        const float w10 = (vx1 && vy0) ? fx * gy : 0.f;
        const float w01 = (vx0 && vy1) ? gx * fy : 0.f;
        const float w11 = (vx1 && vy1) ? fx * fy : 0.f;
        const float* vl = vb + (size_t)starts[l] * D_;
        const float sample = w00 * vl[(size_t)(cy0 * Wl + cx0) * D_] +
                             w10 * vl[(size_t)(cy0 * Wl + cx1) * D_] +
                             w01 * vl[(size_t)(cy1 * Wl + cx0) * D_] +
                             w11 * vl[(size_t)(cy1 * Wl + cx1) * D_];
        acc += aw * sample;
    }
    core[(size_t)bq * D_ + h * HD_ + lane] = acc;
}

// ---------------------------------------------------------------------------
extern "C" void kernel_launch(void* const* d_in, const int* in_sizes, int n_in,
                              void* d_out, int out_size, void* d_ws, size_t ws_size,
                              hipStream_t stream) {
    const float* query = (const float*)d_in[0];
    const float* rp    = (const float*)d_in[1];
    const float* flat  = (const float*)d_in[2];
    // d_in[3], d_in[4]: spatial shapes / level starts — compile-time constants here
    const float* Wv    = (const float*)d_in[5];
    const float* bv    = (const float*)d_in[6];
    const float* Woff  = (const float*)d_in[7];
    const float* boff  = (const float*)d_in[8];
    const float* Wattn = (const float*)d_in[9];
    const float* battn = (const float*)d_in[10];
    const float* Wout  = (const float*)d_in[11];
    const float* bout  = (const float*)d_in[12];

    float* out      = (float*)d_out;                       // (B,NQ,D)
    float* out_loc  = out + (size_t)M_ * D_;               // (B,NQ,NH,NL,NP,2)
    float* out_attn = out_loc + (size_t)M_ * D_;           // (B,NQ,NH,NL,NP)

    float* ws_value = (float*)d_ws;                        // (B,NK,D)
    float* ws_core  = ws_value + (size_t)M_ * D_;          // (B,NQ,D)

    dim3 blk(256);
    // 1. value = input_flatten @ Wv + bv
    gemm_k<256, 0><<<dim3(M_ / 64, 4), blk, 0, stream>>>(flat, Wv, bv, ws_value, nullptr);
    // 2. loc = rp + (query @ Woff + boff)/norm  (fused epilogue, direct to output)
    gemm_k<256, 1><<<dim3(M_ / 64, 4), blk, 0, stream>>>(query, Woff, boff, out_loc, rp);
    // 3. attn logits = query @ Wattn + battn  (direct to attn output region)
    gemm_k<128, 0><<<dim3(M_ / 64, 2), blk, 0, stream>>>(query, Wattn, battn, out_attn, nullptr);
    // 4. softmax (in-place on attn region) + deformable sampling -> ws_core
    deform_core<<<dim3(M_ * NH_ / 8), blk, 0, stream>>>(ws_value, out_loc, out_attn, ws_core);
    // 5. output = core @ Wout + bout
    gemm_k<256, 0><<<dim3(M_ / 64, 4), blk, 0, stream>>>(ws_core, Wout, bout, out, nullptr);
}

// Round 2
// 491.752 us; speedup vs baseline: 1.4138x; 1.4138x over previous
//
#include <hip/hip_runtime.h>
#include <cstdint>
#include <cstddef>

// Fixed problem constants (from reference setup)
#define B_    2
#define NQ_   21760
#define NK_   21760
#define D_    256
#define NH_   8
#define NL_   4
#define NP_   4
#define HD_   32
#define M_    (B_ * NQ_)   // 43520 rows for every GEMM; 43520 = 340 * 128

typedef _Float16 f16x8 __attribute__((ext_vector_type(8)));
typedef float    f32x4 __attribute__((ext_vector_type(4)));

// ---------------------------------------------------------------------------
// Weight prep: W[K=256][N] fp32  ->  Bt[N][256] f16 (transposed + rounded)
// ---------------------------------------------------------------------------
template <int N>
__global__ __launch_bounds__(256) void wconv(const float* __restrict__ W,
                                             _Float16* __restrict__ Bt) {
    int id = blockIdx.x * 256 + threadIdx.x;
    if (id >= 256 * N) return;
    int k = id / N, n = id % N;               // read coalesced along n
    Bt[n * 256 + k] = (_Float16)W[k * N + n]; // scattered 2B writes; tiny matrix
}

// ---------------------------------------------------------------------------
// Split-f16 MFMA GEMM: C[M,N] = A[M,256] @ B[256,N] + bias
// A is fp32, split in-kernel into Ah + Al (f16 each) -> A effectively exact.
// B passed pre-transposed/rounded: Bt[N][256] f16.
// Tile 128x128, 256 threads = 4 waves (2x2), each wave 4x4 frags of 16x16x32.
// EPI==1: loc transform epilogue: out = rp[row,l,c] + val/(128>>l)
// ---------------------------------------------------------------------------
template <int N, int EPI>
__global__ __launch_bounds__(256) void gemm_mfma(const float* __restrict__ A,
                                                 const _Float16* __restrict__ Bt,
                                                 const float* __restrict__ bias,
                                                 float* __restrict__ C,
                                                 const float* __restrict__ rp) {
    constexpr int K = 256;
    constexpr int BK = 32;
    constexpr int LDA = 40;  // padded stride (halves): 80B rows, 16B-aligned, banks spread
    __shared__ _Float16 Ah[128 * LDA];
    __shared__ _Float16 Al[128 * LDA];
    __shared__ _Float16 Bs[128 * LDA];

    const int tid  = threadIdx.x;
    const int m0   = blockIdx.x * 128;
    const int n0   = blockIdx.y * 128;

    const int wave = tid >> 6;
    const int lane = tid & 63;
    const int wm   = (wave & 1) * 64;
    const int wn   = (wave >> 1) * 64;
    const int lm   = lane & 15;
    const int quad = lane >> 4;

    // staging: thread t handles row t>>1, k-halves (t&1)*16 .. +15
    const int ar = tid >> 1;
    const int ac = (tid & 1) * 16;
    const float*    Ag = A  + (size_t)(m0 + ar) * K + ac;
    const _Float16* Bg = Bt + (size_t)(n0 + ar) * K + ac;

    f32x4 acc[4][4];
#pragma unroll
    for (int i = 0; i < 4; ++i)
#pragma unroll
        for (int j = 0; j < 4; ++j) acc[i][j] = (f32x4){0.f, 0.f, 0.f, 0.f};

    for (int k0 = 0; k0 < K; k0 += BK) {
        float a0[16];
        *(float4*)(a0 + 0)  = *(const float4*)(Ag + k0 + 0);
        *(float4*)(a0 + 4)  = *(const float4*)(Ag + k0 + 4);
        *(float4*)(a0 + 8)  = *(const float4*)(Ag + k0 + 8);
        *(float4*)(a0 + 12) = *(const float4*)(Ag + k0 + 12);
        f16x8 b0 = *(const f16x8*)(Bg + k0);
        f16x8 b1 = *(const f16x8*)(Bg + k0 + 8);
        __syncthreads();
        _Float16 hi[16], lo[16];
#pragma unroll
        for (int t = 0; t < 16; ++t) {
            _Float16 h = (_Float16)a0[t];
            hi[t] = h;
            lo[t] = (_Float16)(a0[t] - (float)h);
        }
        *(f16x8*)&Ah[ar * LDA + ac + 0] = *(f16x8*)(hi + 0);
        *(f16x8*)&Ah[ar * LDA + ac + 8] = *(f16x8*)(hi + 8);
        *(f16x8*)&Al[ar * LDA + ac + 0] = *(f16x8*)(lo + 0);
        *(f16x8*)&Al[ar * LDA + ac + 8] = *(f16x8*)(lo + 8);
        *(f16x8*)&Bs[ar * LDA + ac + 0] = b0;
        *(f16x8*)&Bs[ar * LDA + ac + 8] = b1;
        __syncthreads();

        f16x8 af[4], alf[4], bf[4];
#pragma unroll
        for (int i = 0; i < 4; ++i) {
            af[i]  = *(const f16x8*)&Ah[(wm + i * 16 + lm) * LDA + quad * 8];
            alf[i] = *(const f16x8*)&Al[(wm + i * 16 + lm) * LDA + quad * 8];
            bf[i]  = *(const f16x8*)&Bs[(wn + i * 16 + lm) * LDA + quad * 8];
        }
#pragma unroll
        for (int i = 0; i < 4; ++i)
#pragma unroll
            for (int j = 0; j < 4; ++j) {
                acc[i][j] = __builtin_amdgcn_mfma_f32_16x16x32_f16(af[i],  bf[j], acc[i][j], 0, 0, 0);
                acc[i][j] = __builtin_amdgcn_mfma_f32_16x16x32_f16(alf[i], bf[j], acc[i][j], 0, 0, 0);
            }
    }

    // epilogue: C/D layout col=lane&15, row=quad*4+reg  [m89/m91 verified]
    float bcol[4];
#pragma unroll
    for (int j = 0; j < 4; ++j) bcol[j] = bias[n0 + wn + j * 16 + lm];
#pragma unroll
    for (int i = 0; i < 4; ++i)
#pragma unroll
        for (int j = 0; j < 4; ++j) {
            const int col = n0 + wn + j * 16 + lm;
#pragma unroll
            for (int r = 0; r < 4; ++r) {
                const int row = m0 + wm + i * 16 + quad * 4 + r;
                float val = acc[i][j][r] + bcol[j];
                if (EPI == 1) {
                    const int c = col & 1;
                    const int l = (col >> 3) & 3;
                    const float inv = 1.f / (float)(128 >> l);
                    val = rp[(size_t)row * 8 + l * 2 + c] + val * inv;
                }
                C[(size_t)row * N + col] = val;
            }
        }
}

// ---------------------------------------------------------------------------
// Deformable sampling core (unchanged from round 1).
// One 32-lane unit per (b,q,h); lane = channel d in [0,32).
// ---------------------------------------------------------------------------
__global__ __launch_bounds__(256) void deform_core(const float* __restrict__ value,
                                                   const float* __restrict__ loc,
                                                   float* __restrict__ attn,
                                                   float* __restrict__ core) {
    const int tid  = threadIdx.x;
    const int lane = tid & 31;
    const int u    = blockIdx.x * 8 + (tid >> 5);  // (b,q,h) index, h fastest
    const int h    = u & 7;
    const int bq   = u >> 3;
    const int b    = (bq >= NQ_) ? 1 : 0;

    const float myloc = loc[(size_t)u * 32 + lane];  // (NL,NP,2) = 32 floats

    float lg = -1e30f;
    if (lane < 16) lg = attn[(size_t)u * 16 + lane];
    float m = lg;
#pragma unroll
    for (int mk = 8; mk; mk >>= 1) m = fmaxf(m, __shfl_xor(m, mk, 32));
    const float e = __expf(lg - m);
    float s = e;
#pragma unroll
    for (int mk = 8; mk; mk >>= 1) s += __shfl_xor(s, mk, 32);
    const float a = e / s;
    if (lane < 16) attn[(size_t)u * 16 + lane] = a;

    const float* vb = value + (size_t)b * NK_ * D_ + h * HD_ + lane;
    float acc = 0.f;
    const int starts[4] = {0, 16384, 20480, 21504};
#pragma unroll
    for (int j = 0; j < 16; ++j) {
        const int l  = j >> 2;
        const int Wl = 128 >> l;  // square levels: H == W
        const float aw = __shfl(a, j, 32);
        const float xr = __shfl(myloc, 2 * j, 32);
        const float yr = __shfl(myloc, 2 * j + 1, 32);
        const float x = xr * (float)Wl - 0.5f;
        const float y = yr * (float)Wl - 0.5f;
        const float x0f = floorf(x), y0f = floorf(y);
        const int x0 = (int)x0f, y0 = (int)y0f;
        const float fx = x - x0f, fy = y - y0f;
        const float gx = 1.f - fx, gy = 1.f - fy;
        const bool vx0 = (x0 >= 0) && (x0 < Wl);
        const bool vx1 = (x0 >= -1) && (x0 < Wl - 1);
        const bool vy0 = (y0 >= 0) && (y0 < Wl);
        const bool vy1 = (y0 >= -1) && (y0 < Wl - 1);
        const int cx0 = min(max(x0, 0), Wl - 1);
        const int cx1 = min(max(x0 + 1, 0), Wl - 1);
        const int cy0 = min(max(y0, 0), Wl - 1);
        const int cy1 = min(max(y0 + 1, 0), Wl - 1);
        const float w00 = (vx0 && vy0) ? gx * gy : 0.f;
        const float w10 = (vx1 && vy0) ? fx * gy : 0.f;
        const float w01 = (vx0 && vy1) ? gx * fy : 0.f;
        const float w11 = (vx1 && vy1) ? fx * fy : 0.f;
        const float* vl = vb + (size_t)starts[l] * D_;
        const float sample = w00 * vl[(size_t)(cy0 * Wl + cx0) * D_] +
                             w10 * vl[(size_t)(cy0 * Wl + cx1) * D_] +
                             w01 * vl[(size_t)(cy1 * Wl + cx0) * D_] +
                             w11 * vl[(size_t)(cy1 * Wl + cx1) * D_];
        acc += aw * sample;
    }
    core[(size_t)bq * D_ + h * HD_ + lane] = acc;
}

// ---------------------------------------------------------------------------
extern "C" void kernel_launch(void* const* d_in, const int* in_sizes, int n_in,
                              void* d_out, int out_size, void* d_ws, size_t ws_size,
                              hipStream_t stream) {
    const float* query = (const float*)d_in[0];
    const float* rp    = (const float*)d_in[1];
    const float* flat  = (const float*)d_in[2];
    // d_in[3], d_in[4]: spatial shapes / level starts — compile-time constants here
    const float* Wv    = (const float*)d_in[5];
    const float* bv    = (const float*)d_in[6];
    const float* Woff  = (const float*)d_in[7];
    const float* boff  = (const float*)d_in[8];
    const float* Wattn = (const float*)d_in[9];
    const float* battn = (const float*)d_in[10];
    const float* Wout  = (const float*)d_in[11];
    const float* bout  = (const float*)d_in[12];

    float* out      = (float*)d_out;                       // (B,NQ,D)
    float* out_loc  = out + (size_t)M_ * D_;               // (B,NQ,NH,NL,NP,2)
    float* out_attn = out_loc + (size_t)M_ * D_;           // (B,NQ,NH,NL,NP)

    // ws layout: f16 transposed weights first, then fp32 value/core
    _Float16* Bv_t    = (_Float16*)d_ws;                   // [256][256]
    _Float16* Boff_t  = Bv_t + 256 * 256;                  // [256][256]
    _Float16* Battn_t = Boff_t + 256 * 256;                // [128][256]
    _Float16* Bout_t  = Battn_t + 128 * 256;               // [256][256]
    float* ws_value   = (float*)(Bout_t + 256 * 256);      // (B,NK,D)
    float* ws_core    = ws_value + (size_t)M_ * D_;        // (B,NQ,D)

    dim3 blk(256);
    // 0. weight prep (transpose + f16 round)
    wconv<256><<<dim3(256), blk, 0, stream>>>(Wv, Bv_t);
    wconv<256><<<dim3(256), blk, 0, stream>>>(Woff, Boff_t);
    wconv<128><<<dim3(128), blk, 0, stream>>>(Wattn, Battn_t);
    wconv<256><<<dim3(256), blk, 0, stream>>>(Wout, Bout_t);

    // 1. value = input_flatten @ Wv + bv
    gemm_mfma<256, 0><<<dim3(M_ / 128, 2), blk, 0, stream>>>(flat, Bv_t, bv, ws_value, nullptr);
    // 2. loc = rp + (query @ Woff + boff)/norm  (fused epilogue, direct to output)
    gemm_mfma<256, 1><<<dim3(M_ / 128, 2), blk, 0, stream>>>(query, Boff_t, boff, out_loc, rp);
    // 3. attn logits = query @ Wattn + battn  (direct to attn output region)
    gemm_mfma<128, 0><<<dim3(M_ / 128, 1), blk, 0, stream>>>(query, Battn_t, battn, out_attn, nullptr);
    // 4. softmax (in-place on attn region) + deformable sampling -> ws_core
    deform_core<<<dim3(M_ * NH_ / 8), blk, 0, stream>>>(ws_value, out_loc, out_attn, ws_core);
    // 5. output = core @ Wout + bout
    gemm_mfma<256, 0><<<dim3(M_ / 128, 2), blk, 0, stream>>>(ws_core, Bout_t, bout, out, nullptr);
}

// Round 3
// 435.768 us; speedup vs baseline: 1.5955x; 1.1285x over previous
//
#include <hip/hip_runtime.h>
#include <cstdint>
#include <cstddef>

// Fixed problem constants (from reference setup)
#define B_    2
#define NQ_   21760
#define NK_   21760
#define D_    256
#define NH_   8
#define NL_   4
#define NP_   4
#define HD_   32
#define M_    (B_ * NQ_)   // 43520 rows for every GEMM; 43520 = 340 * 128

typedef _Float16 f16x8 __attribute__((ext_vector_type(8)));
typedef float    f32x4 __attribute__((ext_vector_type(4)));

// ---------------------------------------------------------------------------
// Weight prep: W[K=256][N] fp32  ->  Bt[N][256] f16 (transposed + rounded)
// ---------------------------------------------------------------------------
template <int N>
__global__ __launch_bounds__(256) void wconv(const float* __restrict__ W,
                                             _Float16* __restrict__ Bt) {
    int id = blockIdx.x * 256 + threadIdx.x;
    if (id >= 256 * N) return;
    int k = id / N, n = id % N;               // read coalesced along n
    Bt[n * 256 + k] = (_Float16)W[k * N + n]; // scattered 2B writes; tiny matrix
}

// ---------------------------------------------------------------------------
// Split-f16 MFMA GEMM: C[M,N] = A[M,256] @ B[256,N] + bias
// A is fp32, split in-kernel into Ah + Al (f16 each) -> A effectively exact.
// B passed pre-transposed/rounded: Bt[N][256] f16.
// Tile 128x128, 256 threads = 4 waves (2x2), each wave 4x4 frags of 16x16x32.
// EPI==1: loc transform epilogue: out = rp[row,l,c] + val/(128>>l)
// ---------------------------------------------------------------------------
template <int N, int EPI>
__global__ __launch_bounds__(256) void gemm_mfma(const float* __restrict__ A,
                                                 const _Float16* __restrict__ Bt,
                                                 const float* __restrict__ bias,
                                                 float* __restrict__ C,
                                                 const float* __restrict__ rp) {
    constexpr int K = 256;
    constexpr int BK = 32;
    constexpr int LDA = 40;  // padded stride (halves): 80B rows, 16B-aligned, banks spread
    __shared__ _Float16 Ah[128 * LDA];
    __shared__ _Float16 Al[128 * LDA];
    __shared__ _Float16 Bs[128 * LDA];

    const int tid  = threadIdx.x;
    const int m0   = blockIdx.x * 128;
    const int n0   = blockIdx.y * 128;

    const int wave = tid >> 6;
    const int lane = tid & 63;
    const int wm   = (wave & 1) * 64;
    const int wn   = (wave >> 1) * 64;
    const int lm   = lane & 15;
    const int quad = lane >> 4;

    // staging: thread t handles row t>>1, k-halves (t&1)*16 .. +15
    const int ar = tid >> 1;
    const int ac = (tid & 1) * 16;
    const float*    Ag = A  + (size_t)(m0 + ar) * K + ac;
    const _Float16* Bg = Bt + (size_t)(n0 + ar) * K + ac;

    f32x4 acc[4][4];
#pragma unroll
    for (int i = 0; i < 4; ++i)
#pragma unroll
        for (int j = 0; j < 4; ++j) acc[i][j] = (f32x4){0.f, 0.f, 0.f, 0.f};

    for (int k0 = 0; k0 < K; k0 += BK) {
        float a0[16];
        *(float4*)(a0 + 0)  = *(const float4*)(Ag + k0 + 0);
        *(float4*)(a0 + 4)  = *(const float4*)(Ag + k0 + 4);
        *(float4*)(a0 + 8)  = *(const float4*)(Ag + k0 + 8);
        *(float4*)(a0 + 12) = *(const float4*)(Ag + k0 + 12);
        f16x8 b0 = *(const f16x8*)(Bg + k0);
        f16x8 b1 = *(const f16x8*)(Bg + k0 + 8);
        __syncthreads();
        _Float16 hi[16], lo[16];
#pragma unroll
        for (int t = 0; t < 16; ++t) {
            _Float16 h = (_Float16)a0[t];
            hi[t] = h;
            lo[t] = (_Float16)(a0[t] - (float)h);
        }
        *(f16x8*)&Ah[ar * LDA + ac + 0] = *(f16x8*)(hi + 0);
        *(f16x8*)&Ah[ar * LDA + ac + 8] = *(f16x8*)(hi + 8);
        *(f16x8*)&Al[ar * LDA + ac + 0] = *(f16x8*)(lo + 0);
        *(f16x8*)&Al[ar * LDA + ac + 8] = *(f16x8*)(lo + 8);
        *(f16x8*)&Bs[ar * LDA + ac + 0] = b0;
        *(f16x8*)&Bs[ar * LDA + ac + 8] = b1;
        __syncthreads();

        f16x8 af[4], alf[4], bf[4];
#pragma unroll
        for (int i = 0; i < 4; ++i) {
            af[i]  = *(const f16x8*)&Ah[(wm + i * 16 + lm) * LDA + quad * 8];
            alf[i] = *(const f16x8*)&Al[(wm + i * 16 + lm) * LDA + quad * 8];
            bf[i]  = *(const f16x8*)&Bs[(wn + i * 16 + lm) * LDA + quad * 8];
        }
#pragma unroll
        for (int i = 0; i < 4; ++i)
#pragma unroll
            for (int j = 0; j < 4; ++j) {
                acc[i][j] = __builtin_amdgcn_mfma_f32_16x16x32_f16(af[i],  bf[j], acc[i][j], 0, 0, 0);
                acc[i][j] = __builtin_amdgcn_mfma_f32_16x16x32_f16(alf[i], bf[j], acc[i][j], 0, 0, 0);
            }
    }

    // epilogue: C/D layout col=lane&15, row=quad*4+reg  [m89/m91 verified]
    float bcol[4];
#pragma unroll
    for (int j = 0; j < 4; ++j) bcol[j] = bias[n0 + wn + j * 16 + lm];
#pragma unroll
    for (int i = 0; i < 4; ++i)
#pragma unroll
        for (int j = 0; j < 4; ++j) {
            const int col = n0 + wn + j * 16 + lm;
#pragma unroll
            for (int r = 0; r < 4; ++r) {
                const int row = m0 + wm + i * 16 + quad * 4 + r;
                float val = acc[i][j][r] + bcol[j];
                if (EPI == 1) {
                    const int c = col & 1;
                    const int l = (col >> 3) & 3;
                    const float inv = 1.f / (float)(128 >> l);
                    val = rp[(size_t)row * 8 + l * 2 + c] + val * inv;
                }
                C[(size_t)row * N + col] = val;
            }
        }
}

// ---------------------------------------------------------------------------
// Deformable sampling core, tap-parallel layout.
// One 32-lane unit per (b,q,h):
//   lane = tap (lane>>3, 0..3)  x  channel-group (lane&7, float4 each).
// Each lane loads a float4 for ITS tap only (global_load_dwordx4), computes
// only its own tap weight, accumulates w*aw*v4 privately over 16 samples;
// tap-sum deferred to one shfl_xor(8,16) reduction at the end.
// ---------------------------------------------------------------------------
__global__ __launch_bounds__(256) void deform_core(const float* __restrict__ value,
                                                   const float* __restrict__ loc,
                                                   float* __restrict__ attn,
                                                   float* __restrict__ core) {
    const int tid  = threadIdx.x;
    const int lane = tid & 31;
    const int u    = blockIdx.x * 8 + (tid >> 5);  // (b,q,h) index, h fastest
    const int h    = u & 7;
    const int bq   = u >> 3;
    const int b    = (bq >= NQ_) ? 1 : 0;

    const int tap = lane >> 3;      // 0..3
    const int dx  = tap & 1;
    const int dy  = tap >> 1;
    const int c4  = (lane & 7) << 2;  // channel-group base: 0,4,...,28

    const float myloc = loc[(size_t)u * 32 + lane];  // 32 floats = 16 samples x (x,y)

    // softmax over 16 logits (lanes 0..15 hold them), in-place on attn output
    float lg = -1e30f;
    if (lane < 16) lg = attn[(size_t)u * 16 + lane];
    float m = lg;
#pragma unroll
    for (int mk = 8; mk; mk >>= 1) m = fmaxf(m, __shfl_xor(m, mk, 32));
    const float e = __expf(lg - m);
    float s = e;
#pragma unroll
    for (int mk = 8; mk; mk >>= 1) s += __shfl_xor(s, mk, 32);
    const float a = e / s;
    if (lane < 16) attn[(size_t)u * 16 + lane] = a;

    // value base for this (b,h,channel-group), in float4 units (row stride = 64 float4)
    const float4* vb = (const float4*)(value + (size_t)b * NK_ * D_ + h * HD_ + c4);

    float4 acc = {0.f, 0.f, 0.f, 0.f};
    const int starts[4] = {0, 16384, 20480, 21504};
#pragma unroll
    for (int j = 0; j < 16; ++j) {
        const int l  = j >> 2;
        const int Wl = 128 >> l;  // square levels: H == W
        const float aw = __shfl(a, j, 32);
        const float xr = __shfl(myloc, 2 * j, 32);
        const float yr = __shfl(myloc, 2 * j + 1, 32);
        const float x = xr * (float)Wl - 0.5f;
        const float y = yr * (float)Wl - 0.5f;
        const float x0f = floorf(x), y0f = floorf(y);
        const float fx = x - x0f, fy = y - y0f;
        const int xi = (int)x0f + dx;
        const int yi = (int)y0f + dy;
        const float wx = dx ? fx : 1.f - fx;
        const float wy = dy ? fy : 1.f - fy;
        const bool valid = (xi >= 0) && (xi < Wl) && (yi >= 0) && (yi < Wl);
        const float w = valid ? wx * wy * aw : 0.f;
        const int cx = min(max(xi, 0), Wl - 1);
        const int cy = min(max(yi, 0), Wl - 1);
        const float4 v = vb[(size_t)(starts[l] + cy * Wl + cx) * 64];
        acc.x += w * v.x;
        acc.y += w * v.y;
        acc.z += w * v.z;
        acc.w += w * v.w;
    }

    // reduce over taps: lanes {c, c+8, c+16, c+24} hold the same channel group
#pragma unroll
    for (int mk = 8; mk <= 16; mk <<= 1) {
        acc.x += __shfl_xor(acc.x, mk, 32);
        acc.y += __shfl_xor(acc.y, mk, 32);
        acc.z += __shfl_xor(acc.z, mk, 32);
        acc.w += __shfl_xor(acc.w, mk, 32);
    }
    if (lane < 8)
        *(float4*)&core[(size_t)bq * D_ + h * HD_ + c4] = acc;
}

// ---------------------------------------------------------------------------
extern "C" void kernel_launch(void* const* d_in, const int* in_sizes, int n_in,
                              void* d_out, int out_size, void* d_ws, size_t ws_size,
                              hipStream_t stream) {
    const float* query = (const float*)d_in[0];
    const float* rp    = (const float*)d_in[1];
    const float* flat  = (const float*)d_in[2];
    // d_in[3], d_in[4]: spatial shapes / level starts — compile-time constants here
    const float* Wv    = (const float*)d_in[5];
    const float* bv    = (const float*)d_in[6];
    const float* Woff  = (const float*)d_in[7];
    const float* boff  = (const float*)d_in[8];
    const float* Wattn = (const float*)d_in[9];
    const float* battn = (const float*)d_in[10];
    const float* Wout  = (const float*)d_in[11];
    const float* bout  = (const float*)d_in[12];

    float* out      = (float*)d_out;                       // (B,NQ,D)
    float* out_loc  = out + (size_t)M_ * D_;               // (B,NQ,NH,NL,NP,2)
    float* out_attn = out_loc + (size_t)M_ * D_;           // (B,NQ,NH,NL,NP)

    // ws layout: f16 transposed weights first, then fp32 value/core
    _Float16* Bv_t    = (_Float16*)d_ws;                   // [256][256]
    _Float16* Boff_t  = Bv_t + 256 * 256;                  // [256][256]
    _Float16* Battn_t = Boff_t + 256 * 256;                // [128][256]
    _Float16* Bout_t  = Battn_t + 128 * 256;               // [256][256]
    float* ws_value   = (float*)(Bout_t + 256 * 256);      // (B,NK,D)
    float* ws_core    = ws_value + (size_t)M_ * D_;        // (B,NQ,D)

    dim3 blk(256);
    // 0. weight prep (transpose + f16 round)
    wconv<256><<<dim3(256), blk, 0, stream>>>(Wv, Bv_t);
    wconv<256><<<dim3(256), blk, 0, stream>>>(Woff, Boff_t);
    wconv<128><<<dim3(128), blk, 0, stream>>>(Wattn, Battn_t);
    wconv<256><<<dim3(256), blk, 0, stream>>>(Wout, Bout_t);

    // 1. value = input_flatten @ Wv + bv
    gemm_mfma<256, 0><<<dim3(M_ / 128, 2), blk, 0, stream>>>(flat, Bv_t, bv, ws_value, nullptr);
    // 2. loc = rp + (query @ Woff + boff)/norm  (fused epilogue, direct to output)
    gemm_mfma<256, 1><<<dim3(M_ / 128, 2), blk, 0, stream>>>(query, Boff_t, boff, out_loc, rp);
    // 3. attn logits = query @ Wattn + battn  (direct to attn output region)
    gemm_mfma<128, 0><<<dim3(M_ / 128, 1), blk, 0, stream>>>(query, Battn_t, battn, out_attn, nullptr);
    // 4. softmax (in-place on attn region) + deformable sampling -> ws_core
    deform_core<<<dim3(M_ * NH_ / 8), blk, 0, stream>>>(ws_value, out_loc, out_attn, ws_core);
    // 5. output = core @ Wout + bout
    gemm_mfma<256, 0><<<dim3(M_ / 128, 2), blk, 0, stream>>>(ws_core, Bout_t, bout, out, nullptr);
}

// Round 4
// 372.886 us; speedup vs baseline: 1.8645x; 1.1686x over previous
//
#include <hip/hip_runtime.h>
#include <cstdint>
#include <cstddef>

// Fixed problem constants (from reference setup)
#define B_    2
#define NQ_   21760
#define NK_   21760
#define D_    256
#define NH_   8
#define NL_   4
#define NP_   4
#define HD_   32
#define M_    (B_ * NQ_)   // 43520 = 340 * 128

typedef _Float16 f16x8 __attribute__((ext_vector_type(8)));
typedef _Float16 f16x4 __attribute__((ext_vector_type(4)));
typedef float    f32x4 __attribute__((ext_vector_type(4)));

// async global->LDS, 16B per lane; LDS dest = wave-uniform base + lane*16 [m97/m104]
__device__ __forceinline__ void lds16(const _Float16* g, _Float16* l) {
    __builtin_amdgcn_global_load_lds((const __attribute__((address_space(1))) void*)g,
                                     (__attribute__((address_space(3))) void*)l,
                                     16, 0, 0);
}

// ---------------------------------------------------------------------------
// Weight prep (all 4 in one launch): W[K][N] fp32 -> Bt[N][256] f16 transposed
// ---------------------------------------------------------------------------
__global__ __launch_bounds__(256) void wconv_all(const float* __restrict__ Wv,
                                                 const float* __restrict__ Woff,
                                                 const float* __restrict__ Wattn,
                                                 const float* __restrict__ Wout,
                                                 _Float16* __restrict__ Bv_t,
                                                 _Float16* __restrict__ Boff_t,
                                                 _Float16* __restrict__ Battn_t,
                                                 _Float16* __restrict__ Bout_t) {
    int id = blockIdx.x * 256 + threadIdx.x;
    if (id < 65536) {
        int k = id >> 8, n = id & 255;
        Bv_t[n * 256 + k] = (_Float16)Wv[k * 256 + n];
    } else if (id < 131072) {
        int e = id - 65536, k = e >> 8, n = e & 255;
        Boff_t[n * 256 + k] = (_Float16)Woff[k * 256 + n];
    } else if (id < 163840) {
        int e = id - 131072, k = e >> 7, n = e & 127;
        Battn_t[n * 256 + k] = (_Float16)Wattn[k * 128 + n];
    } else if (id < 229376) {
        int e = id - 163840, k = e >> 8, n = e & 255;
        Bout_t[n * 256 + k] = (_Float16)Wout[k * 256 + n];
    }
}

// ---------------------------------------------------------------------------
// fp32 -> f16 row conversion (one float4 -> one f16x4 per thread)
// ---------------------------------------------------------------------------
__global__ __launch_bounds__(256) void aconv(const float* __restrict__ X,
                                             _Float16* __restrict__ Y, int n4) {
    int id = blockIdx.x * 256 + threadIdx.x;
    if (id >= n4) return;
    float4 v = ((const float4*)X)[id];
    f16x4 o = {(_Float16)v.x, (_Float16)v.y, (_Float16)v.z, (_Float16)v.w};
    ((f16x4*)Y)[id] = o;
}

// ---------------------------------------------------------------------------
// f16 MFMA GEMM, m97-style: C[M,N] = A[M,256] @ Bt^T + bias
//   A: [M][256] f16 row-major; Bt: [N][256] f16 (pre-transposed weights)
// Tile 128x128, 256 thr = 4 waves (2x2), 4x4 frags 16x16x32, BK=32.
// Staging: global_load_lds width-16, XOR-swizzled 16B chunks:
//   LDS row r (32 f16 = 4 chunks); lds chunk q holds global chunk q ^ ((r>>1)&3)
//   -> fragment ds_read_b128 has max 2-way bank aliasing (free, m136).
// EPI: 0 = fp32 store, 1 = loc epilogue fp32, 2 = f16 store (value)
// ---------------------------------------------------------------------------
template <int N, int EPI>
__global__ __launch_bounds__(256) void gemm_f16(const _Float16* __restrict__ A,
                                                const _Float16* __restrict__ Bt,
                                                const float* __restrict__ bias,
                                                void* __restrict__ Cv,
                                                const float* __restrict__ rp) {
    constexpr int K = 256;
    constexpr int BK = 32;
    __shared__ _Float16 As[128 * 32];  // 8 KB
    __shared__ _Float16 Bs[128 * 32];  // 8 KB

    const int tid  = threadIdx.x;
    const int wave = tid >> 6;
    const int lane = tid & 63;
    const int m0 = blockIdx.x * 128;
    const int n0 = blockIdx.y * 128;
    const int wm = (wave & 1) << 6;
    const int wn = (wave >> 1) << 6;
    const int lm = lane & 15;
    const int quad = lane >> 4;

    // staging: wave stages rows [wave*32, wave*32+32) of As and Bs, 2 insts each
    // lane covers row srow (inst1) / srow+16 (inst2), lds chunk (lane&3),
    // which must hold global chunk g = (lane&3) ^ ((srow>>1)&3)  (same for +16)
    const int srow = (wave << 5) + (lane >> 2);
    const int g    = (lane & 3) ^ ((lane >> 3) & 3);
    const _Float16* Ag = A  + (size_t)(m0 + srow) * K + (g << 3);
    const _Float16* Bg = Bt + (size_t)(n0 + srow) * K + (g << 3);
    _Float16* AsW = &As[(wave << 5) * 32];
    _Float16* BsW = &Bs[(wave << 5) * 32];

    // fragment read: row = w*+i*16+lm, logical chunk = quad,
    // stored at lds chunk quad ^ ((lm>>1)&3)   [(row>>1)&3 == (lm>>1)&3]
    const int aswz = (quad ^ ((lm >> 1) & 3)) << 3;

    f32x4 acc[4][4];
#pragma unroll
    for (int i = 0; i < 4; ++i)
#pragma unroll
        for (int j = 0; j < 4; ++j) acc[i][j] = (f32x4){0.f, 0.f, 0.f, 0.f};

    for (int k0 = 0; k0 < K; k0 += BK) {
        if (k0) __syncthreads();  // prev iteration's ds_reads done before overwrite
        lds16(Ag + k0,                 AsW);
        lds16(Ag + (size_t)16 * K + k0, AsW + 16 * 32);
        lds16(Bg + k0,                 BsW);
        lds16(Bg + (size_t)16 * K + k0, BsW + 16 * 32);
        __syncthreads();          // drains vmcnt(0): tiles resident

        f16x8 af[4], bf[4];
#pragma unroll
        for (int i = 0; i < 4; ++i)
            af[i] = *(const f16x8*)&As[(wm + i * 16 + lm) * 32 + aswz];
#pragma unroll
        for (int j = 0; j < 4; ++j)
            bf[j] = *(const f16x8*)&Bs[(wn + j * 16 + lm) * 32 + aswz];
#pragma unroll
        for (int i = 0; i < 4; ++i)
#pragma unroll
            for (int j = 0; j < 4; ++j)
                acc[i][j] = __builtin_amdgcn_mfma_f32_16x16x32_f16(af[i], bf[j], acc[i][j], 0, 0, 0);
    }

    // epilogue: C/D layout col=lane&15, row=quad*4+reg  [m89/m91 verified]
    float bcol[4];
#pragma unroll
    for (int j = 0; j < 4; ++j) bcol[j] = bias[n0 + wn + j * 16 + lm];
#pragma unroll
    for (int i = 0; i < 4; ++i)
#pragma unroll
        for (int j = 0; j < 4; ++j) {
            const int col = n0 + wn + j * 16 + lm;
#pragma unroll
            for (int r = 0; r < 4; ++r) {
                const int row = m0 + wm + i * 16 + quad * 4 + r;
                float val = acc[i][j][r] + bcol[j];
                if (EPI == 1) {
                    const int c = col & 1;
                    const int l = (col >> 3) & 3;
                    const float inv = 1.f / (float)(128 >> l);
                    val = rp[(size_t)row * 8 + l * 2 + c] + val * inv;
                }
                if (EPI == 2)
                    ((_Float16*)Cv)[(size_t)row * N + col] = (_Float16)val;
                else
                    ((float*)Cv)[(size_t)row * N + col] = val;
            }
        }
}

// ---------------------------------------------------------------------------
// Deformable sampling core, setup-hoisted tap-parallel layout.
// One 32-lane unit per (b,q,h).
// Setup: lane owns pairs p = lane, lane+32 (p = sample*4 + tap); computes
//   weight (incl. attn) + flat element offset for its pairs ONCE.
// Main loop (16 iters): lane = tap(lane>>3) x chan-group(lane&7):
//   2 shfl broadcasts + one f16x4 (8B) gather + 4 FMA. Tap-reduce at end.
// value is f16 [B][NK][256]; writes core f16 [M][256].
// ---------------------------------------------------------------------------
__global__ __launch_bounds__(256) void deform_core(const _Float16* __restrict__ value,
                                                   const float* __restrict__ loc,
                                                   float* __restrict__ attn,
                                                   _Float16* __restrict__ core) {
    const int tid  = threadIdx.x;
    const int lane = tid & 31;
    const int u    = blockIdx.x * 8 + (tid >> 5);  // (b,q,h), h fastest
    const int h    = u & 7;
    const int bq   = u >> 3;
    const int b    = (bq >= NQ_) ? 1 : 0;

    const float myloc = loc[(size_t)u * 32 + lane];  // (l,p,c) 32 floats

    // softmax over 16 logits, in-place on attn output
    float lg = -1e30f;
    if (lane < 16) lg = attn[(size_t)u * 16 + lane];
    float m = lg;
#pragma unroll
    for (int mk = 8; mk; mk >>= 1) m = fmaxf(m, __shfl_xor(m, mk, 32));
    const float e = __expf(lg - m);
    float s = e;
#pragma unroll
    for (int mk = 8; mk; mk >>= 1) s += __shfl_xor(s, mk, 32);
    const float a = e / s;
    if (lane < 16) attn[(size_t)u * 16 + lane] = a;

    // ---- setup: per-(sample,tap) weight + offset, 2 pairs per lane ----
    int   off[2];
    float w[2];
#pragma unroll
    for (int t2 = 0; t2 < 2; ++t2) {
        const int p  = lane + (t2 << 5);   // pair id 0..63
        const int j  = p >> 2;             // sample 0..15 (l = j>>2, pt = j&3)
        const int dx = p & 1;
        const int dy = (p >> 1) & 1;
        const int l  = j >> 2;
        const int Wl = 128 >> l;
        const int st = (int)((0x15141000u >> (l << 3)) & 0xFFu) << 10;  // level starts
        const float aw = __shfl(a, j, 32);
        const float xr = __shfl(myloc, 2 * j, 32);
        const float yr = __shfl(myloc, 2 * j + 1, 32);
        const float x = xr * (float)Wl - 0.5f;
        const float y = yr * (float)Wl - 0.5f;
        const float x0f = floorf(x), y0f = floorf(y);
        const float fx = x - x0f, fy = y - y0f;
        const int xi = (int)x0f + dx;
        const int yi = (int)y0f + dy;
        const float wx = dx ? fx : 1.f - fx;
        const float wy = dy ? fy : 1.f - fy;
        const bool valid = (xi >= 0) && (xi < Wl) && (yi >= 0) && (yi < Wl);
        w[t2] = valid ? wx * wy * aw : 0.f;
        const int cx = min(max(xi, 0), Wl - 1);
        const int cy = min(max(yi, 0), Wl - 1);
        off[t2] = st + cy * Wl + cx;
    }

    // ---- main loop ----
    const int t = lane >> 3;               // my tap
    const _Float16* vb = value + (size_t)b * NK_ * D_ + h * HD_ + ((lane & 7) << 2);
    float4 acc = {0.f, 0.f, 0.f, 0.f};
#pragma unroll
    for (int j = 0; j < 8; ++j) {          // pairs 4j+t in slot 0
        const int src = (j << 2) + t;
        const float ww = __shfl(w[0], src, 32);
        const int   oo = __shfl(off[0], src, 32);
        const f16x4 v = *(const f16x4*)(vb + (size_t)oo * 256);
        acc.x += ww * (float)v[0];
        acc.y += ww * (float)v[1];
        acc.z += ww * (float)v[2];
        acc.w += ww * (float)v[3];
    }
#pragma unroll
    for (int j = 0; j < 8; ++j) {          // pairs 4(j+8)+t -> slot 1, src = 4j+t
        const int src = (j << 2) + t;
        const float ww = __shfl(w[1], src, 32);
        const int   oo = __shfl(off[1], src, 32);
        const f16x4 v = *(const f16x4*)(vb + (size_t)oo * 256);
        acc.x += ww * (float)v[0];
        acc.y += ww * (float)v[1];
        acc.z += ww * (float)v[2];
        acc.w += ww * (float)v[3];
    }

    // tap reduction: lanes {c, c+8, c+16, c+24} share a channel group
#pragma unroll
    for (int mk = 8; mk <= 16; mk <<= 1) {
        acc.x += __shfl_xor(acc.x, mk, 32);
        acc.y += __shfl_xor(acc.y, mk, 32);
        acc.z += __shfl_xor(acc.z, mk, 32);
        acc.w += __shfl_xor(acc.w, mk, 32);
    }
    if (lane < 8) {
        f16x4 o = {(_Float16)acc.x, (_Float16)acc.y, (_Float16)acc.z, (_Float16)acc.w};
        *(f16x4*)&core[(size_t)bq * 256 + h * 32 + ((lane & 7) << 2)] = o;
    }
}

// ---------------------------------------------------------------------------
extern "C" void kernel_launch(void* const* d_in, const int* in_sizes, int n_in,
                              void* d_out, int out_size, void* d_ws, size_t ws_size,
                              hipStream_t stream) {
    const float* query = (const float*)d_in[0];
    const float* rp    = (const float*)d_in[1];
    const float* flat  = (const float*)d_in[2];
    const float* Wv    = (const float*)d_in[5];
    const float* bv    = (const float*)d_in[6];
    const float* Woff  = (const float*)d_in[7];
    const float* boff  = (const float*)d_in[8];
    const float* Wattn = (const float*)d_in[9];
    const float* battn = (const float*)d_in[10];
    const float* Wout  = (const float*)d_in[11];
    const float* bout  = (const float*)d_in[12];

    float* out      = (float*)d_out;                 // (B,NQ,D)
    float* out_loc  = out + (size_t)M_ * D_;         // (B,NQ,NH,NL,NP,2)
    float* out_attn = out_loc + (size_t)M_ * D_;     // (B,NQ,NH,NL,NP)

    // ws: f16 weights + f16 activations
    _Float16* Bv_t    = (_Float16*)d_ws;             // [256][256]
    _Float16* Boff_t  = Bv_t + 65536;                // [256][256]
    _Float16* Battn_t = Boff_t + 65536;              // [128][256]
    _Float16* Bout_t  = Battn_t + 32768;             // [256][256]
    _Float16* flat16  = Bout_t + 65536;              // [M][256]
    _Float16* query16 = flat16 + (size_t)M_ * 256;   // [M][256]
    _Float16* value16 = query16 + (size_t)M_ * 256;  // [M][256]
    _Float16* core16  = value16 + (size_t)M_ * 256;  // [M][256]

    dim3 blk(256);
    // 0. weight prep (one launch)
    wconv_all<<<dim3(896), blk, 0, stream>>>(Wv, Woff, Wattn, Wout,
                                             Bv_t, Boff_t, Battn_t, Bout_t);
    // 0b. activation f16 conversion
    aconv<<<dim3(M_ * 64 / 256), blk, 0, stream>>>(flat, flat16, M_ * 64);
    aconv<<<dim3(M_ * 64 / 256), blk, 0, stream>>>(query, query16, M_ * 64);

    // 1. value16 = f16(flat @ Wv + bv)
    gemm_f16<256, 2><<<dim3(M_ / 128, 2), blk, 0, stream>>>(flat16, Bv_t, bv, value16, nullptr);
    // 2. loc = rp + (query @ Woff + boff)/norm  (direct to output)
    gemm_f16<256, 1><<<dim3(M_ / 128, 2), blk, 0, stream>>>(query16, Boff_t, boff, out_loc, rp);
    // 3. attn logits (direct to attn output; softmaxed in-place by deform_core)
    gemm_f16<128, 0><<<dim3(M_ / 128, 1), blk, 0, stream>>>(query16, Battn_t, battn, out_attn, nullptr);
    // 4. softmax + deformable sampling -> core16
    deform_core<<<dim3(M_ * NH_ / 8), blk, 0, stream>>>(value16, out_loc, out_attn, core16);
    // 5. out = core @ Wout + bout
    gemm_f16<256, 0><<<dim3(M_ / 128, 2), blk, 0, stream>>>(core16, Bout_t, bout, out, nullptr);
}